// Round 1
// baseline (301.160 us; speedup 1.0000x reference)
//
#include <hip/hip_runtime.h>
#include <hip/hip_fp16.h>
#include <math.h>

// ---------------------------------------------------------------------------
// GAT 2-layer forward, N=50000, E=800000 (+N self loops), EMB=128,
// layer1: heads=8, C=16 (concat -> 128), layer2: heads=1, C=64.
// CSR-by-dst build per call, one gather pass per layer, softmax without
// max-subtraction. h1/h2/act1 fp16. MFMA GEMMs with augmented-weight alpha
// fusion (R9). 8-copy hist + padded cursor (R10/R11). R12: unroll-4 batched
// loads in agg loops.
// R13: FEATURE-SLICED XCD-RESIDENT AGGREGATION.
//   agg1: h1/als/ald stored head-major [head][n][..]; head q pinned to XCD q
//         (blockIdx&7). Per-XCD gather working set = 1.6MB+0.2MB -> L2-fits
//         (was 12.8MB vs 4MB L2 -> HBM misses). 8 lanes/node, 2 lanes/edge.
//   agg2: h2 stored [half][n][32ch]; XCD = (dst-quarter, ch-half). 3.2MB
//         slice L2-fits. 8 lanes/node, 4 lanes/edge.
//   gemm1/gemm2 epilogues emit the sliced layouts; act1 stays node-major.
// ---------------------------------------------------------------------------

typedef _Float16 f16x8 __attribute__((ext_vector_type(8)));
typedef float f32x4 __attribute__((ext_vector_type(4)));

#define PAD 16  // ints per cursor slot (64B line)

__device__ __forceinline__ float leaky_exp(float e) {
    e = (e > 0.f) ? e : 0.2f * e;
    return __expf(e);
}

// accumulate 8 fp16 channels (one float4 = 8 halves) with weight w
__device__ __forceinline__ void acc8(float w, float4 hv,
                                     float* __restrict__ acc) {
    const __half2* hp = (const __half2*)&hv;
#pragma unroll
    for (int k = 0; k < 4; k++) {
        float2 f = __half22float2(hp[k]);
        acc[2 * k] += w * f.x;
        acc[2 * k + 1] += w * f.y;
    }
}

// 8-copy histogram: copy c = blockIdx&7 -> per-XCD atomic lines.
__global__ __launch_bounds__(256) void hist_kernel(const int* __restrict__ dst, int E,
                                                   int* __restrict__ deg8) {
    int c = blockIdx.x & 7;
    int i = (blockIdx.x * 256 + threadIdx.x) * 4;
    if (i + 3 < E) {
        int4 d = *(const int4*)(dst + i);
        atomicAdd(&deg8[d.x * 8 + c], 1);
        atomicAdd(&deg8[d.y * 8 + c], 1);
        atomicAdd(&deg8[d.z * 8 + c], 1);
        atomicAdd(&deg8[d.w * 8 + c], 1);
    } else {
        for (int k = i; k < E; k++) atomicAdd(&deg8[dst[k] * 8 + c], 1);
    }
}

__global__ __launch_bounds__(256) void scan1_kernel(const int* __restrict__ deg8, int N,
                                                    int* __restrict__ rowstart,
                                                    int* __restrict__ blocksum) {
    __shared__ int tmp[256];
    int t = threadIdx.x;
    int i = blockIdx.x * 256 + t;
    int v = 0;
    if (i < N) {
        int4 a = *(const int4*)(deg8 + i * 8);
        int4 b = *(const int4*)(deg8 + i * 8 + 4);
        v = a.x + a.y + a.z + a.w + b.x + b.y + b.z + b.w;
    }
    tmp[t] = v;
    __syncthreads();
    for (int off = 1; off < 256; off <<= 1) {
        int x = (t >= off) ? tmp[t - off] : 0;
        __syncthreads();
        tmp[t] += x;
        __syncthreads();
    }
    if (i < N) rowstart[i] = tmp[t] - v;
    if (t == 255) blocksum[blockIdx.x] = tmp[t];
}

__global__ __launch_bounds__(256) void scan23_kernel(int* __restrict__ rowstart,
                                                     const int* __restrict__ blocksum,
                                                     int nb,
                                                     int* __restrict__ cursor,
                                                     int N, int E) {
    __shared__ int sdata[256];
    int t = threadIdx.x;
    int b = blockIdx.x;
    sdata[t] = (t < nb && t < b) ? blocksum[t] : 0;
    __syncthreads();
#pragma unroll
    for (int off = 128; off > 0; off >>= 1) {
        if (t < off) sdata[t] += sdata[t + off];
        __syncthreads();
    }
    int offset = sdata[0];
    int i = b * 256 + t;
    if (i < N) {
        int v = rowstart[i] + offset;
        rowstart[i] = v;
        cursor[i * PAD] = v;
    } else if (i == N) {
        rowstart[N] = E;
    }
}

// Bucketed scatter: block (blockIdx&7) commits only dst in its 1/8 range.
__global__ __launch_bounds__(256) void scatter_kernel(const int* __restrict__ src,
                                                      const int* __restrict__ dst,
                                                      int E, int N,
                                                      int* __restrict__ cursor,
                                                      int* __restrict__ esrc) {
    int b = blockIdx.x & 7;
    int chunk = blockIdx.x >> 3;
    int bdiv = (N + 7) >> 3;
    int blo = b * bdiv;
    int bhi = blo + bdiv;
    int base = chunk * 1024 + threadIdx.x;
#pragma unroll
    for (int u = 0; u < 4; u++) {
        int i = base + u * 256;
        if (i < E) {
            int d = dst[i];
            int s = src[i];
            if (d >= blo && d < bhi) {
                int p = atomicAdd(&cursor[d * PAD], 1);
                esrc[p] = s;
            }
        }
    }
}

// Prep: build transposed fp16 augmented weights.
__global__ __launch_bounds__(256) void augw_kernel(const float* __restrict__ W1,
                                                   const float* __restrict__ a1s,
                                                   const float* __restrict__ a1d,
                                                   const float* __restrict__ W2,
                                                   const float* __restrict__ a2s,
                                                   const float* __restrict__ a2d,
                                                   _Float16* __restrict__ W1t,
                                                   _Float16* __restrict__ W2t) {
    int t = threadIdx.x;
    if (blockIdx.x == 0) {
        for (int i = t; i < 144 * 128; i += 256) {
            int c = i >> 7, k = i & 127;
            float v;
            if (c < 128) {
                v = W1[k * 128 + c];
            } else if (c < 136) {
                int h = c - 128; v = 0.f;
#pragma unroll
                for (int j = 0; j < 16; j++) v += W1[k * 128 + h * 16 + j] * a1s[h * 16 + j];
            } else {
                int h = c - 136; v = 0.f;
#pragma unroll
                for (int j = 0; j < 16; j++) v += W1[k * 128 + h * 16 + j] * a1d[h * 16 + j];
            }
            W1t[c * 128 + k] = (_Float16)v;
        }
    } else {
        for (int i = t; i < 80 * 128; i += 256) {
            int c = i >> 7, k = i & 127;
            float v = 0.f;
            if (c < 64) {
                v = W2[k * 64 + c];
            } else if (c == 64) {
                for (int j = 0; j < 64; j++) v += W2[k * 64 + j] * a2s[j];
            } else if (c == 65) {
                for (int j = 0; j < 64; j++) v += W2[k * 64 + j] * a2d[j];
            }
            W2t[c * 128 + k] = (_Float16)v;
        }
    }
}

// MFMA GEMM1: 64 rows x 144 cols per block (4 waves x 16 rows, 9 col-frags).
// R13: h1 written HEAD-MAJOR [head][n][16]; als/ald head-major [head][n].
__global__ __launch_bounds__(256) void gemm1_kernel(const float* __restrict__ x,
                                                    const _Float16* __restrict__ W1t,
                                                    __half* __restrict__ h1,
                                                    float* __restrict__ als,
                                                    float* __restrict__ ald, int N) {
    __shared__ _Float16 Xs[64 * 136];  // 17 KB
    int t = threadIdx.x;
    int row0 = blockIdx.x * 64;
    for (int i = t; i < 2048; i += 256) {
        int r = i >> 5, c4 = i & 31;
        int gr = row0 + r;
        float4 v = make_float4(0.f, 0.f, 0.f, 0.f);
        if (gr < N) v = *(const float4*)(x + (size_t)gr * 128 + c4 * 4);
        _Float16* dp = Xs + r * 136 + c4 * 4;
        dp[0] = (_Float16)v.x; dp[1] = (_Float16)v.y;
        dp[2] = (_Float16)v.z; dp[3] = (_Float16)v.w;
    }
    __syncthreads();
    int w = t >> 6, L = t & 63, m = L & 15, quad = L >> 4;
    f32x4 acc[9];
#pragma unroll
    for (int f = 0; f < 9; f++) acc[f] = (f32x4){0.f, 0.f, 0.f, 0.f};
    const _Float16* Arow = Xs + (w * 16 + m) * 136 + quad * 8;
    const _Float16* Brow = W1t + m * 128 + quad * 8;
#pragma unroll
    for (int kt = 0; kt < 4; kt++) {
        f16x8 a = *(const f16x8*)(Arow + kt * 32);
#pragma unroll
        for (int f = 0; f < 9; f++) {
            f16x8 b = *(const f16x8*)(Brow + f * 2048 + kt * 32);
            acc[f] = __builtin_amdgcn_mfma_f32_16x16x32_f16(a, b, acc[f], 0, 0, 0);
        }
    }
    int nbase = row0 + w * 16 + quad * 4;
#pragma unroll
    for (int r = 0; r < 4; r++) {
        int n = nbase + r;
        if (n < N) {
#pragma unroll
            for (int f = 0; f < 8; f++)
                h1[((size_t)f * N + n) * 16 + m] = __float2half(acc[f][r]);
            float v = acc[8][r];
            if (m < 8) als[(size_t)m * N + n] = v;
            else ald[(size_t)(m - 8) * N + n] = v;
        }
    }
}

// Aggregation layer 1 (R13): head q pinned to XCD q (blockIdx&7). Per-XCD
// gather set = h1 head slice (1.6MB) + als slice (0.2MB) -> L2-resident.
// 8 lanes/node: slot=k>>1 (4 edges in flight), half=k&1 (8 channels each).
__global__ __launch_bounds__(256) void agg1_kernel(const __half* __restrict__ h1,
                                                   const float* __restrict__ als,
                                                   const float* __restrict__ ald,
                                                   const int* __restrict__ rowstart,
                                                   const int* __restrict__ esrc,
                                                   const float* __restrict__ b1,
                                                   __half* __restrict__ act1, int N) {
    int t = threadIdx.x;
    int q = blockIdx.x & 7;   // head -> XCD
    int g = t >> 3;           // node group within block (32 nodes/block)
    int k = t & 7;            // lane in group
    int slot = k >> 1;        // edge slot 0..3
    int half = k & 1;         // channel half (8 ch)
    int n = (blockIdx.x >> 3) * 32 + g;
    if (n >= N) return;
    const size_t qN = (size_t)q * N;
    const float4* h1v = (const float4*)h1;
    float adv = ald[qN + n];
    float acc[8];
#pragma unroll
    for (int c = 0; c < 8; c++) acc[c] = 0.f;
    float wsum = 0.f;
    if (slot == 0) {  // self loop: once per half
        float w = leaky_exp(als[qN + n] + adv);
        wsum += w;
        acc8(w, h1v[(qN + n) * 2 + half], acc);
    }
    int beg = rowstart[n], end = rowstart[n + 1];
    int j = beg;
    for (; j + 8 <= end; j += 8) {  // 8 edges / group-iter, 2 per lane
        int s0 = esrc[j + slot], s1 = esrc[j + 4 + slot];
        float4 a0 = h1v[(qN + s0) * 2 + half];
        float4 a1 = h1v[(qN + s1) * 2 + half];
        float e0 = als[qN + s0], e1 = als[qN + s1];
        float w0 = leaky_exp(e0 + adv), w1 = leaky_exp(e1 + adv);
        wsum += w0 + w1;
        acc8(w0, a0, acc);
        acc8(w1, a1, acc);
    }
    for (; j + 4 <= end; j += 4) {
        int s0 = esrc[j + slot];
        float4 a0 = h1v[(qN + s0) * 2 + half];
        float w0 = leaky_exp(als[qN + s0] + adv);
        wsum += w0;
        acc8(w0, a0, acc);
    }
    if (j + slot < end) {
        int s0 = esrc[j + slot];
        float4 a0 = h1v[(qN + s0) * 2 + half];
        float w0 = leaky_exp(als[qN + s0] + adv);
        wsum += w0;
        acc8(w0, a0, acc);
    }
    // reduce across the 4 edge slots; xor 2/4 preserve half parity
#pragma unroll
    for (int off = 2; off <= 4; off <<= 1) {
        wsum += __shfl_xor(wsum, off);
#pragma unroll
        for (int c = 0; c < 8; c++) acc[c] += __shfl_xor(acc[c], off);
    }
    if (k < 2) {  // k==half here; lanes 0,1 write the two channel halves
        float inv = 1.f / (wsum + 1e-16f);
        const float* bf = b1 + q * 16 + k * 8;
        __align__(16) __half2 po[4];
#pragma unroll
        for (int c = 0; c < 4; c++) {
            float o0 = acc[2 * c] * inv + bf[2 * c];
            float o1 = acc[2 * c + 1] * inv + bf[2 * c + 1];
            o0 = (o0 > 0.f) ? o0 : (__expf(o0) - 1.f);  // ELU
            o1 = (o1 > 0.f) ? o1 : (__expf(o1) - 1.f);
            po[c] = __floats2half2_rn(o0, o1);
        }
        *(float4*)(act1 + (size_t)n * 128 + q * 16 + k * 8) = *(float4*)po;
    }
}

// MFMA GEMM2: 64 rows x 80 cols per block; A-frags from global act1 (fp16),
// B-frags from W2t (L1-resident). No LDS.
// R13: h2 written HALF-MAJOR [half][n][32] for the channel-sliced agg2.
__global__ __launch_bounds__(256) void gemm2_kernel(const __half* __restrict__ act1,
                                                    const _Float16* __restrict__ W2t,
                                                    __half* __restrict__ h2,
                                                    float* __restrict__ al2s,
                                                    float* __restrict__ al2d, int N) {
    int t = threadIdx.x;
    int row0 = blockIdx.x * 64;
    int w = t >> 6, L = t & 63, m = L & 15, quad = L >> 4;
    f32x4 acc[5];
#pragma unroll
    for (int f = 0; f < 5; f++) acc[f] = (f32x4){0.f, 0.f, 0.f, 0.f};
    const _Float16* Arow =
        (const _Float16*)act1 + (size_t)(row0 + w * 16 + m) * 128 + quad * 8;
    const _Float16* Brow = W2t + m * 128 + quad * 8;
#pragma unroll
    for (int kt = 0; kt < 4; kt++) {
        f16x8 a = *(const f16x8*)(Arow + kt * 32);
#pragma unroll
        for (int f = 0; f < 5; f++) {
            f16x8 b = *(const f16x8*)(Brow + f * 2048 + kt * 32);
            acc[f] = __builtin_amdgcn_mfma_f32_16x16x32_f16(a, b, acc[f], 0, 0, 0);
        }
    }
    int nbase = row0 + w * 16 + quad * 4;
#pragma unroll
    for (int r = 0; r < 4; r++) {
        int n = nbase + r;
        if (n < N) {
#pragma unroll
            for (int f = 0; f < 4; f++)
                h2[((size_t)(f >> 1) * N + n) * 32 + (f & 1) * 16 + m] =
                    __float2half(acc[f][r]);
            if (m == 0) al2s[n] = acc[4][r];
            else if (m == 1) al2d[n] = acc[4][r];
        }
    }
}

// Aggregation layer 2 (R13): XCD c handles (ch-half=c&1, dst-quarter=c>>1).
// Per-XCD gather set = h2 half slice (3.2MB) + al2s (0.2MB) -> L2-resident.
// 8 lanes/node: slot=k>>2 (2 edges in flight), cl=k&3 (8 channels each).
__global__ __launch_bounds__(256) void agg2_kernel(const __half* __restrict__ h2,
                                                   const float* __restrict__ al2s,
                                                   const float* __restrict__ al2d,
                                                   const int* __restrict__ rowstart,
                                                   const int* __restrict__ esrc,
                                                   const float* __restrict__ b2,
                                                   float* __restrict__ out, int N) {
    int t = threadIdx.x;
    int c = blockIdx.x & 7;
    int half = c & 1;
    int quarter = c >> 1;
    int g = t >> 3;
    int k = t & 7;
    int slot = k >> 2;  // 0/1
    int cl = k & 3;     // channel lane: 8 ch each
    int qdiv = (N + 3) >> 2;
    int local = (blockIdx.x >> 3) * 32 + g;
    if (local >= qdiv) return;
    int n = quarter * qdiv + local;
    if (n >= N) return;
    const size_t hN = (size_t)half * N;
    const float4* h2v = (const float4*)h2;
    float adv = al2d[n];
    float acc[8];
#pragma unroll
    for (int cc = 0; cc < 8; cc++) acc[cc] = 0.f;
    float wsum = 0.f;
    if (slot == 0) {  // self loop
        float w = leaky_exp(al2s[n] + adv);
        wsum += w;
        acc8(w, h2v[(hN + n) * 4 + cl], acc);
    }
    int beg = rowstart[n], end = rowstart[n + 1];
    int j = beg;
    for (; j + 8 <= end; j += 8) {  // 8 edges / group-iter, 4 per lane
        int s0 = esrc[j + slot], s1 = esrc[j + 2 + slot];
        int s2 = esrc[j + 4 + slot], s3 = esrc[j + 6 + slot];
        float4 a0 = h2v[(hN + s0) * 4 + cl];
        float4 a1 = h2v[(hN + s1) * 4 + cl];
        float4 a2 = h2v[(hN + s2) * 4 + cl];
        float4 a3 = h2v[(hN + s3) * 4 + cl];
        float e0 = al2s[s0], e1 = al2s[s1], e2 = al2s[s2], e3 = al2s[s3];
        float w0 = leaky_exp(e0 + adv), w1 = leaky_exp(e1 + adv);
        float w2 = leaky_exp(e2 + adv), w3 = leaky_exp(e3 + adv);
        wsum += (w0 + w1) + (w2 + w3);
        acc8(w0, a0, acc);
        acc8(w1, a1, acc);
        acc8(w2, a2, acc);
        acc8(w3, a3, acc);
    }
    for (; j + 2 <= end; j += 2) {
        int s0 = esrc[j + slot];
        float4 a0 = h2v[(hN + s0) * 4 + cl];
        float w0 = leaky_exp(al2s[s0] + adv);
        wsum += w0;
        acc8(w0, a0, acc);
    }
    if (j + slot < end) {
        int s0 = esrc[j + slot];
        float4 a0 = h2v[(hN + s0) * 4 + cl];
        float w0 = leaky_exp(al2s[s0] + adv);
        wsum += w0;
        acc8(w0, a0, acc);
    }
    // reduce across the 2 edge slots (xor 4 preserves cl)
    wsum += __shfl_xor(wsum, 4);
#pragma unroll
    for (int cc = 0; cc < 8; cc++) acc[cc] += __shfl_xor(acc[cc], 4);
    if (k < 4) {  // k==cl here; 4 lanes write 32B each -> 128B/node-half
        float inv = 1.f / (wsum + 1e-16f);
        const float* bf = b2 + half * 32 + cl * 8;
        float4* ov = (float4*)(out + (size_t)n * 64 + half * 32 + cl * 8);
        ov[0] = make_float4(acc[0] * inv + bf[0], acc[1] * inv + bf[1],
                            acc[2] * inv + bf[2], acc[3] * inv + bf[3]);
        ov[1] = make_float4(acc[4] * inv + bf[4], acc[5] * inv + bf[5],
                            acc[6] * inv + bf[6], acc[7] * inv + bf[7]);
    }
}

extern "C" void kernel_launch(void* const* d_in, const int* in_sizes, int n_in,
                              void* d_out, int out_size, void* d_ws, size_t ws_size,
                              hipStream_t stream) {
    (void)n_in; (void)out_size; (void)ws_size;
    const float* x   = (const float*)d_in[0];
    const int*   ei  = (const int*)d_in[1];
    const float* W1  = (const float*)d_in[2];
    const float* a1s = (const float*)d_in[3];
    const float* a1d = (const float*)d_in[4];
    const float* b1  = (const float*)d_in[5];
    const float* W2  = (const float*)d_in[6];
    const float* a2s = (const float*)d_in[7];
    const float* a2d = (const float*)d_in[8];
    const float* b2  = (const float*)d_in[9];
    float* out = (float*)d_out;

    const int N = in_sizes[0] / 128;
    const int E = in_sizes[1] / 2;
    const int* src = ei;
    const int* dst = ei + E;

    char* wp = (char*)d_ws;
    auto alloc = [&](size_t bytes) -> void* {
        void* p = (void*)wp;
        wp += (bytes + 255) & ~(size_t)255;
        return p;
    };
    __half* h1   = (__half*)alloc((size_t)N * 128 * 2);
    __half* act1 = (__half*)alloc((size_t)N * 128 * 2);
    __half* h2   = (__half*)alloc((size_t)N * 64 * 2 + 64 * 256);  // +pad for gemm2 tail
    float* al1s = (float*)alloc((size_t)N * 8 * 4);
    float* al1d = (float*)alloc((size_t)N * 8 * 4);
    float* al2s = (float*)alloc((size_t)N * 4);
    float* al2d = (float*)alloc((size_t)N * 4);
    int* deg8     = (int*)alloc((size_t)N * 8 * 4);    // 8 XCD-local copies
    int* rowstart = (int*)alloc((size_t)(N + 1) * 4);
    int* cursor   = (int*)alloc((size_t)N * PAD * 4);  // 1 counter / 64B line
    int* esrc     = (int*)alloc((size_t)E * 4);
    int* blocksum = (int*)alloc(256 * 4);
    _Float16* W1t = (_Float16*)alloc(144 * 128 * 2);
    _Float16* W2t = (_Float16*)alloc(80 * 128 * 2);

    const int nbScan = (N + 255) / 256;
    const int gridH  = (E + 1023) / 1024;
    const int gridG1 = (N + 63) / 64;
    const int gridScat = ((E + 1023) / 1024) * 8;
    const int gridG2 = (N + 63) / 64;
    const int gridAgg1 = 8 * ((N + 31) / 32);
    const int qdiv2 = (N + 3) / 4;
    const int gridAgg2 = 8 * ((qdiv2 + 31) / 32);

    hipMemsetAsync(deg8, 0, (size_t)N * 8 * 4, stream);

    augw_kernel<<<2, 256, 0, stream>>>(W1, a1s, a1d, W2, a2s, a2d, W1t, W2t);
    hist_kernel<<<gridH, 256, 0, stream>>>(dst, E, deg8);
    gemm1_kernel<<<gridG1, 256, 0, stream>>>(x, W1t, h1, al1s, al1d, N);
    scan1_kernel<<<nbScan, 256, 0, stream>>>(deg8, N, rowstart, blocksum);
    scan23_kernel<<<(N + 256) / 256, 256, 0, stream>>>(rowstart, blocksum, nbScan,
                                                       cursor, N, E);
    scatter_kernel<<<gridScat, 256, 0, stream>>>(src, dst, E, N, cursor, esrc);

    agg1_kernel<<<gridAgg1, 256, 0, stream>>>(h1, al1s, al1d, rowstart, esrc, b1, act1, N);
    gemm2_kernel<<<gridG2, 256, 0, stream>>>(act1, W2t, h2, al2s, al2d, N);
    agg2_kernel<<<gridAgg2, 256, 0, stream>>>(h2, al2s, al2d, rowstart, esrc, b2, out, N);
}

// Round 2
// 261.155 us; speedup vs baseline: 1.1532x; 1.1532x over previous
//
#include <hip/hip_runtime.h>
#include <hip/hip_fp16.h>
#include <math.h>

// ---------------------------------------------------------------------------
// GAT 2-layer forward, N=50000, E=800000 (+N self loops), EMB=128,
// layer1: heads=8, C=16 (concat -> 128), layer2: heads=1, C=64.
// CSR-by-dst build per call, one gather pass per layer, softmax without
// max-subtraction. h1/h2/act1 fp16. MFMA GEMMs with augmented-weight alpha
// fusion (R9). 8-copy hist + padded cursor (R10/R11). R12: agg loops
// unrolled x4 with batched loads (TA-throughput floor).
// R14: KERNEL-FUSION OVERLAP (R13's head-slicing reverted — FETCH dropped as
//      predicted but TA address count is layout-invariant; overhead +21us).
//   K1 = augw ∥ hist   (block-range split: blocks 0,1 augw; rest hist)
//   K4 = gemm1 ∥ scatter (blocks [0,gridG1) gemm; rest scatter)
//   The CSR-build chain and the gemm1 chain are independent; fusing them
//   co-schedules MFMA waves with VMEM/atomic waves (separate pipes) without
//   events (forbidden under graph capture). Saves ~min(gemm1,scatter).
// ---------------------------------------------------------------------------

typedef _Float16 f16x8 __attribute__((ext_vector_type(8)));
typedef float f32x4 __attribute__((ext_vector_type(4)));

#define PAD 16  // ints per cursor slot (64B line)

__device__ __forceinline__ float leaky_exp(float e) {
    e = (e > 0.f) ? e : 0.2f * e;
    return __expf(e);
}

__device__ __forceinline__ void acc16(float w, float4 hv0, float4 hv1,
                                      float* __restrict__ acc) {
    const __half2* p0 = (const __half2*)&hv0;
    const __half2* p1 = (const __half2*)&hv1;
#pragma unroll
    for (int k = 0; k < 4; k++) {
        float2 f = __half22float2(p0[k]);
        acc[2 * k] += w * f.x;
        acc[2 * k + 1] += w * f.y;
    }
#pragma unroll
    for (int k = 0; k < 4; k++) {
        float2 f = __half22float2(p1[k]);
        acc[8 + 2 * k] += w * f.x;
        acc[8 + 2 * k + 1] += w * f.y;
    }
}

__device__ __forceinline__ void acc8(float w, float4 hv,
                                     float* __restrict__ acc) {
    const __half2* hp = (const __half2*)&hv;
#pragma unroll
    for (int k = 0; k < 4; k++) {
        float2 f = __half22float2(hp[k]);
        acc[2 * k] += w * f.x;
        acc[2 * k + 1] += w * f.y;
    }
}

// ---------------------------------------------------------------------------
// K1: fused augw ∥ hist. Blocks 0,1 build transposed fp16 augmented weights;
// blocks >=2 run the 8-copy histogram (copy c = bid&7 -> per-XCD atomic lines).
// ---------------------------------------------------------------------------
__global__ __launch_bounds__(256) void augw_hist_kernel(
        const float* __restrict__ W1, const float* __restrict__ a1s,
        const float* __restrict__ a1d, const float* __restrict__ W2,
        const float* __restrict__ a2s, const float* __restrict__ a2d,
        _Float16* __restrict__ W1t, _Float16* __restrict__ W2t,
        const int* __restrict__ dst, int E, int* __restrict__ deg8) {
    int t = threadIdx.x;
    if (blockIdx.x == 0) {
        for (int i = t; i < 144 * 128; i += 256) {
            int c = i >> 7, k = i & 127;
            float v;
            if (c < 128) {
                v = W1[k * 128 + c];
            } else if (c < 136) {
                int h = c - 128; v = 0.f;
#pragma unroll
                for (int j = 0; j < 16; j++) v += W1[k * 128 + h * 16 + j] * a1s[h * 16 + j];
            } else {
                int h = c - 136; v = 0.f;
#pragma unroll
                for (int j = 0; j < 16; j++) v += W1[k * 128 + h * 16 + j] * a1d[h * 16 + j];
            }
            W1t[c * 128 + k] = (_Float16)v;
        }
    } else if (blockIdx.x == 1) {
        for (int i = t; i < 80 * 128; i += 256) {
            int c = i >> 7, k = i & 127;
            float v = 0.f;
            if (c < 64) {
                v = W2[k * 64 + c];
            } else if (c == 64) {
                for (int j = 0; j < 64; j++) v += W2[k * 64 + j] * a2s[j];
            } else if (c == 65) {
                for (int j = 0; j < 64; j++) v += W2[k * 64 + j] * a2d[j];
            }
            W2t[c * 128 + k] = (_Float16)v;
        }
    } else {
        int bid = blockIdx.x - 2;
        int c = bid & 7;
        int i = (bid * 256 + t) * 4;
        if (i + 3 < E) {
            int4 d = *(const int4*)(dst + i);
            atomicAdd(&deg8[d.x * 8 + c], 1);
            atomicAdd(&deg8[d.y * 8 + c], 1);
            atomicAdd(&deg8[d.z * 8 + c], 1);
            atomicAdd(&deg8[d.w * 8 + c], 1);
        } else {
            for (int k = i; k < E; k++) atomicAdd(&deg8[dst[k] * 8 + c], 1);
        }
    }
}

__global__ __launch_bounds__(256) void scan1_kernel(const int* __restrict__ deg8, int N,
                                                    int* __restrict__ rowstart,
                                                    int* __restrict__ blocksum) {
    __shared__ int tmp[256];
    int t = threadIdx.x;
    int i = blockIdx.x * 256 + t;
    int v = 0;
    if (i < N) {
        int4 a = *(const int4*)(deg8 + i * 8);
        int4 b = *(const int4*)(deg8 + i * 8 + 4);
        v = a.x + a.y + a.z + a.w + b.x + b.y + b.z + b.w;
    }
    tmp[t] = v;
    __syncthreads();
    for (int off = 1; off < 256; off <<= 1) {
        int x = (t >= off) ? tmp[t - off] : 0;
        __syncthreads();
        tmp[t] += x;
        __syncthreads();
    }
    if (i < N) rowstart[i] = tmp[t] - v;
    if (t == 255) blocksum[blockIdx.x] = tmp[t];
}

__global__ __launch_bounds__(256) void scan23_kernel(int* __restrict__ rowstart,
                                                     const int* __restrict__ blocksum,
                                                     int nb,
                                                     int* __restrict__ cursor,
                                                     int N, int E) {
    __shared__ int sdata[256];
    int t = threadIdx.x;
    int b = blockIdx.x;
    sdata[t] = (t < nb && t < b) ? blocksum[t] : 0;
    __syncthreads();
#pragma unroll
    for (int off = 128; off > 0; off >>= 1) {
        if (t < off) sdata[t] += sdata[t + off];
        __syncthreads();
    }
    int offset = sdata[0];
    int i = b * 256 + t;
    if (i < N) {
        int v = rowstart[i] + offset;
        rowstart[i] = v;
        cursor[i * PAD] = v;
    } else if (i == N) {
        rowstart[N] = E;
    }
}

// ---------------------------------------------------------------------------
// K4: fused gemm1 ∥ scatter. Blocks [0, gridG1) do the MFMA GEMM1 (64 rows x
// 144 cols per block); blocks [gridG1, gridG1+gridScat) do the bucketed
// scatter (block (sbid&7) commits only dst in its 1/8 range). Independent
// outputs (h1/als/ald vs esrc); MFMA and VMEM/atomic pipes overlap.
// ---------------------------------------------------------------------------
__global__ __launch_bounds__(256) void gemm1_scatter_kernel(
        const float* __restrict__ x, const _Float16* __restrict__ W1t,
        __half* __restrict__ h1, float* __restrict__ als,
        float* __restrict__ ald, int N, int gridG1,
        const int* __restrict__ src, const int* __restrict__ dst, int E,
        int* __restrict__ cursor, int* __restrict__ esrc) {
    __shared__ _Float16 Xs[64 * 136];  // 17 KB
    int t = threadIdx.x;
    if ((int)blockIdx.x >= gridG1) {
        // ---- scatter path ----
        int sbid = blockIdx.x - gridG1;
        int b = sbid & 7;
        int chunk = sbid >> 3;
        int bdiv = (N + 7) >> 3;
        int blo = b * bdiv;
        int bhi = blo + bdiv;
        int base = chunk * 1024 + t;
#pragma unroll
        for (int u = 0; u < 4; u++) {
            int i = base + u * 256;
            if (i < E) {
                int d = dst[i];
                int s = src[i];
                if (d >= blo && d < bhi) {
                    int p = atomicAdd(&cursor[d * PAD], 1);
                    esrc[p] = s;
                }
            }
        }
        return;
    }
    // ---- gemm1 path ----
    int row0 = blockIdx.x * 64;
    for (int i = t; i < 2048; i += 256) {
        int r = i >> 5, c4 = i & 31;
        int gr = row0 + r;
        float4 v = make_float4(0.f, 0.f, 0.f, 0.f);
        if (gr < N) v = *(const float4*)(x + (size_t)gr * 128 + c4 * 4);
        _Float16* dp = Xs + r * 136 + c4 * 4;
        dp[0] = (_Float16)v.x; dp[1] = (_Float16)v.y;
        dp[2] = (_Float16)v.z; dp[3] = (_Float16)v.w;
    }
    __syncthreads();
    int w = t >> 6, L = t & 63, m = L & 15, quad = L >> 4;
    f32x4 acc[9];
#pragma unroll
    for (int f = 0; f < 9; f++) acc[f] = (f32x4){0.f, 0.f, 0.f, 0.f};
    const _Float16* Arow = Xs + (w * 16 + m) * 136 + quad * 8;
    const _Float16* Brow = W1t + m * 128 + quad * 8;
#pragma unroll
    for (int kt = 0; kt < 4; kt++) {
        f16x8 a = *(const f16x8*)(Arow + kt * 32);
#pragma unroll
        for (int f = 0; f < 9; f++) {
            f16x8 b = *(const f16x8*)(Brow + f * 2048 + kt * 32);
            acc[f] = __builtin_amdgcn_mfma_f32_16x16x32_f16(a, b, acc[f], 0, 0, 0);
        }
    }
    int nbase = row0 + w * 16 + quad * 4;
#pragma unroll
    for (int r = 0; r < 4; r++) {
        int n = nbase + r;
        if (n < N) {
            __half* hrow = h1 + (size_t)n * 128 + m;
#pragma unroll
            for (int f = 0; f < 8; f++) hrow[f * 16] = __float2half(acc[f][r]);
            float v = acc[8][r];
            if (m < 8) als[n * 8 + m] = v;
            else ald[n * 8 + (m - 8)] = v;
        }
    }
}

// Aggregation layer 1, node-per-group (8 nodes/wave x 8 lanes, lane q = head
// q's 16 channels), XCD-bucketed; edge loop UNROLLED x4 with batched loads.
__global__ __launch_bounds__(256) void agg1_kernel(const __half* __restrict__ h1,
                                                   const float* __restrict__ als,
                                                   const float* __restrict__ ald,
                                                   const int* __restrict__ rowstart,
                                                   const int* __restrict__ esrc,
                                                   const float* __restrict__ b1,
                                                   __half* __restrict__ act1, int N) {
    int t = threadIdx.x;
    int lane = t & 63;
    int grp = lane >> 3;
    int q = lane & 7;
    int bdiv = (N + 7) >> 3;
    int ln = (blockIdx.x >> 3) * 32 + (t >> 6) * 8 + grp;
    if (ln >= bdiv) return;
    int n = (blockIdx.x & 7) * bdiv + ln;
    if (n >= N) return;
    const float4* h1v = (const float4*)h1;
    float adv = ald[n * 8 + q];
    float acc[16];
#pragma unroll
    for (int k = 0; k < 16; k++) acc[k] = 0.f;
    float wsum = 0.f;
    {  // self loop
        float w = leaky_exp(als[n * 8 + q] + adv);
        wsum += w;
        acc16(w, h1v[(size_t)n * 16 + 2 * q], h1v[(size_t)n * 16 + 2 * q + 1], acc);
    }
    int beg = rowstart[n], end = rowstart[n + 1];
    int j = beg;
    for (; j + 4 <= end; j += 4) {
        int s0 = esrc[j], s1 = esrc[j + 1], s2 = esrc[j + 2], s3 = esrc[j + 3];
        // batch-issue all 12 loads before any use
        float4 a0 = h1v[(size_t)s0 * 16 + 2 * q], b0 = h1v[(size_t)s0 * 16 + 2 * q + 1];
        float4 a1 = h1v[(size_t)s1 * 16 + 2 * q], b1 = h1v[(size_t)s1 * 16 + 2 * q + 1];
        float4 a2 = h1v[(size_t)s2 * 16 + 2 * q], b2 = h1v[(size_t)s2 * 16 + 2 * q + 1];
        float4 a3 = h1v[(size_t)s3 * 16 + 2 * q], b3 = h1v[(size_t)s3 * 16 + 2 * q + 1];
        float e0 = als[s0 * 8 + q], e1 = als[s1 * 8 + q];
        float e2 = als[s2 * 8 + q], e3 = als[s3 * 8 + q];
        float w0 = leaky_exp(e0 + adv), w1 = leaky_exp(e1 + adv);
        float w2 = leaky_exp(e2 + adv), w3 = leaky_exp(e3 + adv);
        wsum += (w0 + w1) + (w2 + w3);
        acc16(w0, a0, b0, acc);
        acc16(w1, a1, b1, acc);
        acc16(w2, a2, b2, acc);
        acc16(w3, a3, b3, acc);
    }
    for (; j < end; j++) {
        int s = esrc[j];
        float w = leaky_exp(als[s * 8 + q] + adv);
        wsum += w;
        acc16(w, h1v[(size_t)s * 16 + 2 * q], h1v[(size_t)s * 16 + 2 * q + 1], acc);
    }
    float inv = 1.f / (wsum + 1e-16f);
    const float* bf = b1 + q * 16;
    __align__(16) __half2 po[8];
#pragma unroll
    for (int k = 0; k < 8; k++) {
        float o0 = acc[2 * k] * inv + bf[2 * k];
        float o1 = acc[2 * k + 1] * inv + bf[2 * k + 1];
        o0 = (o0 > 0.f) ? o0 : (__expf(o0) - 1.f);  // ELU
        o1 = (o1 > 0.f) ? o1 : (__expf(o1) - 1.f);
        po[k] = __floats2half2_rn(o0, o1);
    }
    float4* ov = (float4*)(act1 + (size_t)n * 128 + q * 16);
    ov[0] = ((float4*)po)[0];
    ov[1] = ((float4*)po)[1];
}

// MFMA GEMM2: 64 rows x 80 cols per block; A-frags from global act1 (fp16),
// B-frags from W2t (L1-resident). No LDS.
__global__ __launch_bounds__(256) void gemm2_kernel(const __half* __restrict__ act1,
                                                    const _Float16* __restrict__ W2t,
                                                    __half* __restrict__ h2,
                                                    float* __restrict__ al2s,
                                                    float* __restrict__ al2d, int N) {
    int t = threadIdx.x;
    int row0 = blockIdx.x * 64;
    int w = t >> 6, L = t & 63, m = L & 15, quad = L >> 4;
    f32x4 acc[5];
#pragma unroll
    for (int f = 0; f < 5; f++) acc[f] = (f32x4){0.f, 0.f, 0.f, 0.f};
    const _Float16* Arow =
        (const _Float16*)act1 + (size_t)(row0 + w * 16 + m) * 128 + quad * 8;
    const _Float16* Brow = W2t + m * 128 + quad * 8;
#pragma unroll
    for (int kt = 0; kt < 4; kt++) {
        f16x8 a = *(const f16x8*)(Arow + kt * 32);
#pragma unroll
        for (int f = 0; f < 5; f++) {
            f16x8 b = *(const f16x8*)(Brow + f * 2048 + kt * 32);
            acc[f] = __builtin_amdgcn_mfma_f32_16x16x32_f16(a, b, acc[f], 0, 0, 0);
        }
    }
    int nbase = row0 + w * 16 + quad * 4;
#pragma unroll
    for (int r = 0; r < 4; r++) {
        int n = nbase + r;
        if (n < N) {
            __half* hrow = h2 + (size_t)n * 64 + m;
#pragma unroll
            for (int f = 0; f < 4; f++) hrow[f * 16] = __float2half(acc[f][r]);
            if (m == 0) al2s[n] = acc[4][r];
            else if (m == 1) al2d[n] = acc[4][r];
        }
    }
}

// Aggregation layer 2, node-per-group, XCD-bucketed; lane q owns channels
// 8q..8q+7; edge loop UNROLLED x4 with batched loads.
__global__ __launch_bounds__(256) void agg2_kernel(const __half* __restrict__ h2,
                                                   const float* __restrict__ al2s,
                                                   const float* __restrict__ al2d,
                                                   const int* __restrict__ rowstart,
                                                   const int* __restrict__ esrc,
                                                   const float* __restrict__ b2,
                                                   float* __restrict__ out, int N) {
    int t = threadIdx.x;
    int lane = t & 63;
    int grp = lane >> 3;
    int q = lane & 7;
    int bdiv = (N + 7) >> 3;
    int ln = (blockIdx.x >> 3) * 32 + (t >> 6) * 8 + grp;
    if (ln >= bdiv) return;
    int n = (blockIdx.x & 7) * bdiv + ln;
    if (n >= N) return;
    const float4* h2v = (const float4*)h2;
    float adv = al2d[n];
    float acc[8];
#pragma unroll
    for (int k = 0; k < 8; k++) acc[k] = 0.f;
    float wsum = 0.f;
    {  // self loop
        float w = leaky_exp(al2s[n] + adv);
        wsum += w;
        acc8(w, h2v[(size_t)n * 8 + q], acc);
    }
    int beg = rowstart[n], end = rowstart[n + 1];
    int j = beg;
    for (; j + 4 <= end; j += 4) {
        int s0 = esrc[j], s1 = esrc[j + 1], s2 = esrc[j + 2], s3 = esrc[j + 3];
        float4 a0 = h2v[(size_t)s0 * 8 + q];
        float4 a1 = h2v[(size_t)s1 * 8 + q];
        float4 a2 = h2v[(size_t)s2 * 8 + q];
        float4 a3 = h2v[(size_t)s3 * 8 + q];
        float e0 = al2s[s0], e1 = al2s[s1], e2 = al2s[s2], e3 = al2s[s3];
        float w0 = leaky_exp(e0 + adv), w1 = leaky_exp(e1 + adv);
        float w2 = leaky_exp(e2 + adv), w3 = leaky_exp(e3 + adv);
        wsum += (w0 + w1) + (w2 + w3);
        acc8(w0, a0, acc);
        acc8(w1, a1, acc);
        acc8(w2, a2, acc);
        acc8(w3, a3, acc);
    }
    for (; j < end; j++) {
        int s = esrc[j];
        float w = leaky_exp(al2s[s] + adv);
        wsum += w;
        acc8(w, h2v[(size_t)s * 8 + q], acc);
    }
    float inv = 1.f / (wsum + 1e-16f);
    const float* bf = b2 + q * 8;
    float4* ov = (float4*)(out + (size_t)n * 64 + q * 8);
    ov[0] = make_float4(acc[0] * inv + bf[0], acc[1] * inv + bf[1],
                        acc[2] * inv + bf[2], acc[3] * inv + bf[3]);
    ov[1] = make_float4(acc[4] * inv + bf[4], acc[5] * inv + bf[5],
                        acc[6] * inv + bf[6], acc[7] * inv + bf[7]);
}

extern "C" void kernel_launch(void* const* d_in, const int* in_sizes, int n_in,
                              void* d_out, int out_size, void* d_ws, size_t ws_size,
                              hipStream_t stream) {
    (void)n_in; (void)out_size; (void)ws_size;
    const float* x   = (const float*)d_in[0];
    const int*   ei  = (const int*)d_in[1];
    const float* W1  = (const float*)d_in[2];
    const float* a1s = (const float*)d_in[3];
    const float* a1d = (const float*)d_in[4];
    const float* b1  = (const float*)d_in[5];
    const float* W2  = (const float*)d_in[6];
    const float* a2s = (const float*)d_in[7];
    const float* a2d = (const float*)d_in[8];
    const float* b2  = (const float*)d_in[9];
    float* out = (float*)d_out;

    const int N = in_sizes[0] / 128;
    const int E = in_sizes[1] / 2;
    const int* src = ei;
    const int* dst = ei + E;

    char* wp = (char*)d_ws;
    auto alloc = [&](size_t bytes) -> void* {
        void* p = (void*)wp;
        wp += (bytes + 255) & ~(size_t)255;
        return p;
    };
    __half* h1   = (__half*)alloc((size_t)N * 128 * 2);
    __half* act1 = (__half*)alloc((size_t)N * 128 * 2);
    __half* h2   = (__half*)alloc((size_t)N * 64 * 2 + 64 * 256);  // +pad for gemm2 tail
    float* al1s = (float*)alloc((size_t)N * 8 * 4);
    float* al1d = (float*)alloc((size_t)N * 8 * 4);
    float* al2s = (float*)alloc((size_t)N * 4);
    float* al2d = (float*)alloc((size_t)N * 4);
    int* deg8     = (int*)alloc((size_t)N * 8 * 4);    // 8 XCD-local copies
    int* rowstart = (int*)alloc((size_t)(N + 1) * 4);
    int* cursor   = (int*)alloc((size_t)N * PAD * 4);  // 1 counter / 64B line
    int* esrc     = (int*)alloc((size_t)E * 4);
    int* blocksum = (int*)alloc(256 * 4);
    _Float16* W1t = (_Float16*)alloc(144 * 128 * 2);
    _Float16* W2t = (_Float16*)alloc(80 * 128 * 2);

    const int nbScan = (N + 255) / 256;
    const int gridH  = (E + 1023) / 1024;
    const int gridG1 = (N + 63) / 64;
    const int gridScat = ((E + 1023) / 1024) * 8;
    const int gridG2 = (N + 63) / 64;
    const int bdiv = (N + 7) / 8;
    const int gridAggN = 8 * ((bdiv + 31) / 32);

    hipMemsetAsync(deg8, 0, (size_t)N * 8 * 4, stream);

    // K1: augw ∥ hist
    augw_hist_kernel<<<2 + gridH, 256, 0, stream>>>(W1, a1s, a1d, W2, a2s, a2d,
                                                    W1t, W2t, dst, E, deg8);
    scan1_kernel<<<nbScan, 256, 0, stream>>>(deg8, N, rowstart, blocksum);
    scan23_kernel<<<(N + 256) / 256, 256, 0, stream>>>(rowstart, blocksum, nbScan,
                                                       cursor, N, E);
    // K4: gemm1 ∥ scatter
    gemm1_scatter_kernel<<<gridG1 + gridScat, 256, 0, stream>>>(
        x, W1t, h1, al1s, al1d, N, gridG1, src, dst, E, cursor, esrc);

    agg1_kernel<<<gridAggN, 256, 0, stream>>>(h1, al1s, al1d, rowstart, esrc, b1, act1, N);
    gemm2_kernel<<<gridG2, 256, 0, stream>>>(act1, W2t, h2, al2s, al2d, N);
    agg2_kernel<<<gridAggN, 256, 0, stream>>>(h2, al2s, al2d, rowstart, esrc, b2, out, N);
}

// Round 3
// 257.197 us; speedup vs baseline: 1.1709x; 1.0154x over previous
//
#include <hip/hip_runtime.h>
#include <hip/hip_fp16.h>
#include <math.h>

// ---------------------------------------------------------------------------
// GAT 2-layer forward, N=50000, E=800000 (+N self loops), EMB=128,
// layer1: heads=8, C=16 (concat -> 128), layer2: heads=1, C=64.
// CSR-by-dst build per call, one gather pass per layer, softmax without
// max-subtraction. h1/h2/act1 fp16. MFMA GEMMs with augmented-weight alpha
// fusion (R9). R12: agg loops unrolled x4 with batched loads.
// R14: kernel-fusion overlap (augw ∥ hist; gemm1 ∥ scatter).
// R15: TWO-PHASE BUCKETED SCATTER (kills the 8x redundant edge scan).
//   Phase A (in K1, same pass as hist): block-local LDS ranking into 8
//     dst-range buckets, one global atomicAdd per bucket per block to
//     reserve slots, compacted (src,dst) pair writes into per-bucket lists.
//   Phase B (in K4, replaces old scatter): bucket b processed only by
//     blocks with blockIdx%8==b -> XCD-local cursor atomics as before, but
//     each edge visited ONCE with dense coalesced reads (was 8 scans with
//     1/8 filter = 6.4M visits; now 800k).
// ---------------------------------------------------------------------------

typedef _Float16 f16x8 __attribute__((ext_vector_type(8)));
typedef float f32x4 __attribute__((ext_vector_type(4)));

#define PAD 16  // ints per cursor slot (64B line)

__device__ __forceinline__ float leaky_exp(float e) {
    e = (e > 0.f) ? e : 0.2f * e;
    return __expf(e);
}

__device__ __forceinline__ void acc16(float w, float4 hv0, float4 hv1,
                                      float* __restrict__ acc) {
    const __half2* p0 = (const __half2*)&hv0;
    const __half2* p1 = (const __half2*)&hv1;
#pragma unroll
    for (int k = 0; k < 4; k++) {
        float2 f = __half22float2(p0[k]);
        acc[2 * k] += w * f.x;
        acc[2 * k + 1] += w * f.y;
    }
#pragma unroll
    for (int k = 0; k < 4; k++) {
        float2 f = __half22float2(p1[k]);
        acc[8 + 2 * k] += w * f.x;
        acc[8 + 2 * k + 1] += w * f.y;
    }
}

__device__ __forceinline__ void acc8(float w, float4 hv,
                                     float* __restrict__ acc) {
    const __half2* hp = (const __half2*)&hv;
#pragma unroll
    for (int k = 0; k < 4; k++) {
        float2 f = __half22float2(hp[k]);
        acc[2 * k] += w * f.x;
        acc[2 * k + 1] += w * f.y;
    }
}

// ---------------------------------------------------------------------------
// K1: fused augw ∥ (hist + bucket phase A). Blocks 0,1 build transposed fp16
// augmented weights; blocks >=2: histogram (copy c=bid&7, XCD-local lines)
// AND compacted bucket lists of (src,dst) pairs for phase B.
// ---------------------------------------------------------------------------
__global__ __launch_bounds__(256) void augw_hist_kernel(
        const float* __restrict__ W1, const float* __restrict__ a1s,
        const float* __restrict__ a1d, const float* __restrict__ W2,
        const float* __restrict__ a2s, const float* __restrict__ a2d,
        _Float16* __restrict__ W1t, _Float16* __restrict__ W2t,
        const int* __restrict__ src, const int* __restrict__ dst,
        int E, int N, int* __restrict__ deg8,
        int* __restrict__ bucketCnt, int2* __restrict__ pairs) {
    __shared__ int lcnt[8];
    __shared__ int lbase[8];
    int t = threadIdx.x;
    if (blockIdx.x == 0) {
        for (int i = t; i < 144 * 128; i += 256) {
            int c = i >> 7, k = i & 127;
            float v;
            if (c < 128) {
                v = W1[k * 128 + c];
            } else if (c < 136) {
                int h = c - 128; v = 0.f;
#pragma unroll
                for (int j = 0; j < 16; j++) v += W1[k * 128 + h * 16 + j] * a1s[h * 16 + j];
            } else {
                int h = c - 136; v = 0.f;
#pragma unroll
                for (int j = 0; j < 16; j++) v += W1[k * 128 + h * 16 + j] * a1d[h * 16 + j];
            }
            W1t[c * 128 + k] = (_Float16)v;
        }
        return;
    }
    if (blockIdx.x == 1) {
        for (int i = t; i < 80 * 128; i += 256) {
            int c = i >> 7, k = i & 127;
            float v = 0.f;
            if (c < 64) {
                v = W2[k * 64 + c];
            } else if (c == 64) {
                for (int j = 0; j < 64; j++) v += W2[k * 64 + j] * a2s[j];
            } else if (c == 65) {
                for (int j = 0; j < 64; j++) v += W2[k * 64 + j] * a2d[j];
            }
            W2t[c * 128 + k] = (_Float16)v;
        }
        return;
    }
    // ---- phase A: hist + bucket compaction ----
    if (t < 8) lcnt[t] = 0;
    __syncthreads();
    int bid = blockIdx.x - 2;
    int c = bid & 7;
    int bdiv = (N + 7) >> 3;
    int i0 = (bid * 256 + t) * 4;
    int s_[4], d_[4], bk[4], rk[4];
    int nv = 0;
    if (i0 + 3 < E) {
        int4 d4 = *(const int4*)(dst + i0);
        int4 s4 = *(const int4*)(src + i0);
        s_[0] = s4.x; s_[1] = s4.y; s_[2] = s4.z; s_[3] = s4.w;
        d_[0] = d4.x; d_[1] = d4.y; d_[2] = d4.z; d_[3] = d4.w;
        nv = 4;
    } else {
        for (int k = i0; k < E && nv < 4; k++) {
            s_[nv] = src[k]; d_[nv] = dst[k]; nv++;
        }
    }
#pragma unroll 4
    for (int k = 0; k < nv; k++) {
        atomicAdd(&deg8[d_[k] * 8 + c], 1);
        bk[k] = d_[k] / bdiv;
        rk[k] = atomicAdd(&lcnt[bk[k]], 1);
    }
    __syncthreads();
    if (t < 8) lbase[t] = atomicAdd(&bucketCnt[t * 16], lcnt[t]);
    __syncthreads();
#pragma unroll 4
    for (int k = 0; k < nv; k++) {
        pairs[(size_t)bk[k] * E + lbase[bk[k]] + rk[k]] = make_int2(s_[k], d_[k]);
    }
}

__global__ __launch_bounds__(256) void scan1_kernel(const int* __restrict__ deg8, int N,
                                                    int* __restrict__ rowstart,
                                                    int* __restrict__ blocksum) {
    __shared__ int tmp[256];
    int t = threadIdx.x;
    int i = blockIdx.x * 256 + t;
    int v = 0;
    if (i < N) {
        int4 a = *(const int4*)(deg8 + i * 8);
        int4 b = *(const int4*)(deg8 + i * 8 + 4);
        v = a.x + a.y + a.z + a.w + b.x + b.y + b.z + b.w;
    }
    tmp[t] = v;
    __syncthreads();
    for (int off = 1; off < 256; off <<= 1) {
        int x = (t >= off) ? tmp[t - off] : 0;
        __syncthreads();
        tmp[t] += x;
        __syncthreads();
    }
    if (i < N) rowstart[i] = tmp[t] - v;
    if (t == 255) blocksum[blockIdx.x] = tmp[t];
}

__global__ __launch_bounds__(256) void scan23_kernel(int* __restrict__ rowstart,
                                                     const int* __restrict__ blocksum,
                                                     int nb,
                                                     int* __restrict__ cursor,
                                                     int N, int E) {
    __shared__ int sdata[256];
    int t = threadIdx.x;
    int b = blockIdx.x;
    sdata[t] = (t < nb && t < b) ? blocksum[t] : 0;
    __syncthreads();
#pragma unroll
    for (int off = 128; off > 0; off >>= 1) {
        if (t < off) sdata[t] += sdata[t + off];
        __syncthreads();
    }
    int offset = sdata[0];
    int i = b * 256 + t;
    if (i < N) {
        int v = rowstart[i] + offset;
        rowstart[i] = v;
        cursor[i * PAD] = v;
    } else if (i == N) {
        rowstart[N] = E;
    }
}

// ---------------------------------------------------------------------------
// K4: fused gemm1 ∥ scatter-phase-B. Blocks [0, gridG1) do the MFMA GEMM1;
// blocks >= gridG1 drain bucket lists: bucket b = sbid&7 -> XCD-local cursor
// atomics; dense coalesced int2 reads; each edge visited once.
// ---------------------------------------------------------------------------
__global__ __launch_bounds__(256) void gemm1_scatter_kernel(
        const float* __restrict__ x, const _Float16* __restrict__ W1t,
        __half* __restrict__ h1, float* __restrict__ als,
        float* __restrict__ ald, int N, int gridG1,
        const int* __restrict__ bucketCnt, const int2* __restrict__ pairs,
        int E, int nChunk,
        int* __restrict__ cursor, int* __restrict__ esrc) {
    __shared__ _Float16 Xs[64 * 136];  // 17 KB
    int t = threadIdx.x;
    if ((int)blockIdx.x >= gridG1) {
        // ---- phase B: bucket drain ----
        int sbid = blockIdx.x - gridG1;
        int b = sbid & 7;
        int chunk = sbid >> 3;
        int cnt = bucketCnt[b * 16];
        const int2* plist = pairs + (size_t)b * E;
        for (int ii = chunk * 1024; ii < cnt; ii += nChunk * 1024) {
#pragma unroll
            for (int u = 0; u < 4; u++) {
                int i = ii + u * 256 + t;
                if (i < cnt) {
                    int2 p = plist[i];
                    int pos = atomicAdd(&cursor[p.y * PAD], 1);
                    esrc[pos] = p.x;
                }
            }
        }
        return;
    }
    // ---- gemm1 path ----
    int row0 = blockIdx.x * 64;
    for (int i = t; i < 2048; i += 256) {
        int r = i >> 5, c4 = i & 31;
        int gr = row0 + r;
        float4 v = make_float4(0.f, 0.f, 0.f, 0.f);
        if (gr < N) v = *(const float4*)(x + (size_t)gr * 128 + c4 * 4);
        _Float16* dp = Xs + r * 136 + c4 * 4;
        dp[0] = (_Float16)v.x; dp[1] = (_Float16)v.y;
        dp[2] = (_Float16)v.z; dp[3] = (_Float16)v.w;
    }
    __syncthreads();
    int w = t >> 6, L = t & 63, m = L & 15, quad = L >> 4;
    f32x4 acc[9];
#pragma unroll
    for (int f = 0; f < 9; f++) acc[f] = (f32x4){0.f, 0.f, 0.f, 0.f};
    const _Float16* Arow = Xs + (w * 16 + m) * 136 + quad * 8;
    const _Float16* Brow = W1t + m * 128 + quad * 8;
#pragma unroll
    for (int kt = 0; kt < 4; kt++) {
        f16x8 a = *(const f16x8*)(Arow + kt * 32);
#pragma unroll
        for (int f = 0; f < 9; f++) {
            f16x8 b = *(const f16x8*)(Brow + f * 2048 + kt * 32);
            acc[f] = __builtin_amdgcn_mfma_f32_16x16x32_f16(a, b, acc[f], 0, 0, 0);
        }
    }
    int nbase = row0 + w * 16 + quad * 4;
#pragma unroll
    for (int r = 0; r < 4; r++) {
        int n = nbase + r;
        if (n < N) {
            __half* hrow = h1 + (size_t)n * 128 + m;
#pragma unroll
            for (int f = 0; f < 8; f++) hrow[f * 16] = __float2half(acc[f][r]);
            float v = acc[8][r];
            if (m < 8) als[n * 8 + m] = v;
            else ald[n * 8 + (m - 8)] = v;
        }
    }
}

// Aggregation layer 1, node-per-group (8 nodes/wave x 8 lanes, lane q = head
// q's 16 channels), XCD-bucketed; edge loop UNROLLED x4 with batched loads.
__global__ __launch_bounds__(256) void agg1_kernel(const __half* __restrict__ h1,
                                                   const float* __restrict__ als,
                                                   const float* __restrict__ ald,
                                                   const int* __restrict__ rowstart,
                                                   const int* __restrict__ esrc,
                                                   const float* __restrict__ b1,
                                                   __half* __restrict__ act1, int N) {
    int t = threadIdx.x;
    int lane = t & 63;
    int grp = lane >> 3;
    int q = lane & 7;
    int bdiv = (N + 7) >> 3;
    int ln = (blockIdx.x >> 3) * 32 + (t >> 6) * 8 + grp;
    if (ln >= bdiv) return;
    int n = (blockIdx.x & 7) * bdiv + ln;
    if (n >= N) return;
    const float4* h1v = (const float4*)h1;
    float adv = ald[n * 8 + q];
    float acc[16];
#pragma unroll
    for (int k = 0; k < 16; k++) acc[k] = 0.f;
    float wsum = 0.f;
    {  // self loop
        float w = leaky_exp(als[n * 8 + q] + adv);
        wsum += w;
        acc16(w, h1v[(size_t)n * 16 + 2 * q], h1v[(size_t)n * 16 + 2 * q + 1], acc);
    }
    int beg = rowstart[n], end = rowstart[n + 1];
    int j = beg;
    for (; j + 4 <= end; j += 4) {
        int s0 = esrc[j], s1 = esrc[j + 1], s2 = esrc[j + 2], s3 = esrc[j + 3];
        // batch-issue all 12 loads before any use
        float4 a0 = h1v[(size_t)s0 * 16 + 2 * q], b0 = h1v[(size_t)s0 * 16 + 2 * q + 1];
        float4 a1 = h1v[(size_t)s1 * 16 + 2 * q], b1 = h1v[(size_t)s1 * 16 + 2 * q + 1];
        float4 a2 = h1v[(size_t)s2 * 16 + 2 * q], b2 = h1v[(size_t)s2 * 16 + 2 * q + 1];
        float4 a3 = h1v[(size_t)s3 * 16 + 2 * q], b3 = h1v[(size_t)s3 * 16 + 2 * q + 1];
        float e0 = als[s0 * 8 + q], e1 = als[s1 * 8 + q];
        float e2 = als[s2 * 8 + q], e3 = als[s3 * 8 + q];
        float w0 = leaky_exp(e0 + adv), w1 = leaky_exp(e1 + adv);
        float w2 = leaky_exp(e2 + adv), w3 = leaky_exp(e3 + adv);
        wsum += (w0 + w1) + (w2 + w3);
        acc16(w0, a0, b0, acc);
        acc16(w1, a1, b1, acc);
        acc16(w2, a2, b2, acc);
        acc16(w3, a3, b3, acc);
    }
    for (; j < end; j++) {
        int s = esrc[j];
        float w = leaky_exp(als[s * 8 + q] + adv);
        wsum += w;
        acc16(w, h1v[(size_t)s * 16 + 2 * q], h1v[(size_t)s * 16 + 2 * q + 1], acc);
    }
    float inv = 1.f / (wsum + 1e-16f);
    const float* bf = b1 + q * 16;
    __align__(16) __half2 po[8];
#pragma unroll
    for (int k = 0; k < 8; k++) {
        float o0 = acc[2 * k] * inv + bf[2 * k];
        float o1 = acc[2 * k + 1] * inv + bf[2 * k + 1];
        o0 = (o0 > 0.f) ? o0 : (__expf(o0) - 1.f);  // ELU
        o1 = (o1 > 0.f) ? o1 : (__expf(o1) - 1.f);
        po[k] = __floats2half2_rn(o0, o1);
    }
    float4* ov = (float4*)(act1 + (size_t)n * 128 + q * 16);
    ov[0] = ((float4*)po)[0];
    ov[1] = ((float4*)po)[1];
}

// MFMA GEMM2: 64 rows x 80 cols per block; A-frags from global act1 (fp16),
// B-frags from W2t (L1-resident). No LDS.
__global__ __launch_bounds__(256) void gemm2_kernel(const __half* __restrict__ act1,
                                                    const _Float16* __restrict__ W2t,
                                                    __half* __restrict__ h2,
                                                    float* __restrict__ al2s,
                                                    float* __restrict__ al2d, int N) {
    int t = threadIdx.x;
    int row0 = blockIdx.x * 64;
    int w = t >> 6, L = t & 63, m = L & 15, quad = L >> 4;
    f32x4 acc[5];
#pragma unroll
    for (int f = 0; f < 5; f++) acc[f] = (f32x4){0.f, 0.f, 0.f, 0.f};
    const _Float16* Arow =
        (const _Float16*)act1 + (size_t)(row0 + w * 16 + m) * 128 + quad * 8;
    const _Float16* Brow = W2t + m * 128 + quad * 8;
#pragma unroll
    for (int kt = 0; kt < 4; kt++) {
        f16x8 a = *(const f16x8*)(Arow + kt * 32);
#pragma unroll
        for (int f = 0; f < 5; f++) {
            f16x8 b = *(const f16x8*)(Brow + f * 2048 + kt * 32);
            acc[f] = __builtin_amdgcn_mfma_f32_16x16x32_f16(a, b, acc[f], 0, 0, 0);
        }
    }
    int nbase = row0 + w * 16 + quad * 4;
#pragma unroll
    for (int r = 0; r < 4; r++) {
        int n = nbase + r;
        if (n < N) {
            __half* hrow = h2 + (size_t)n * 64 + m;
#pragma unroll
            for (int f = 0; f < 4; f++) hrow[f * 16] = __float2half(acc[f][r]);
            if (m == 0) al2s[n] = acc[4][r];
            else if (m == 1) al2d[n] = acc[4][r];
        }
    }
}

// Aggregation layer 2, node-per-group, XCD-bucketed; lane q owns channels
// 8q..8q+7; edge loop UNROLLED x4 with batched loads.
__global__ __launch_bounds__(256) void agg2_kernel(const __half* __restrict__ h2,
                                                   const float* __restrict__ al2s,
                                                   const float* __restrict__ al2d,
                                                   const int* __restrict__ rowstart,
                                                   const int* __restrict__ esrc,
                                                   const float* __restrict__ b2,
                                                   float* __restrict__ out, int N) {
    int t = threadIdx.x;
    int lane = t & 63;
    int grp = lane >> 3;
    int q = lane & 7;
    int bdiv = (N + 7) >> 3;
    int ln = (blockIdx.x >> 3) * 32 + (t >> 6) * 8 + grp;
    if (ln >= bdiv) return;
    int n = (blockIdx.x & 7) * bdiv + ln;
    if (n >= N) return;
    const float4* h2v = (const float4*)h2;
    float adv = al2d[n];
    float acc[8];
#pragma unroll
    for (int k = 0; k < 8; k++) acc[k] = 0.f;
    float wsum = 0.f;
    {  // self loop
        float w = leaky_exp(al2s[n] + adv);
        wsum += w;
        acc8(w, h2v[(size_t)n * 8 + q], acc);
    }
    int beg = rowstart[n], end = rowstart[n + 1];
    int j = beg;
    for (; j + 4 <= end; j += 4) {
        int s0 = esrc[j], s1 = esrc[j + 1], s2 = esrc[j + 2], s3 = esrc[j + 3];
        float4 a0 = h2v[(size_t)s0 * 8 + q];
        float4 a1 = h2v[(size_t)s1 * 8 + q];
        float4 a2 = h2v[(size_t)s2 * 8 + q];
        float4 a3 = h2v[(size_t)s3 * 8 + q];
        float e0 = al2s[s0], e1 = al2s[s1], e2 = al2s[s2], e3 = al2s[s3];
        float w0 = leaky_exp(e0 + adv), w1 = leaky_exp(e1 + adv);
        float w2 = leaky_exp(e2 + adv), w3 = leaky_exp(e3 + adv);
        wsum += (w0 + w1) + (w2 + w3);
        acc8(w0, a0, acc);
        acc8(w1, a1, acc);
        acc8(w2, a2, acc);
        acc8(w3, a3, acc);
    }
    for (; j < end; j++) {
        int s = esrc[j];
        float w = leaky_exp(al2s[s] + adv);
        wsum += w;
        acc8(w, h2v[(size_t)s * 8 + q], acc);
    }
    float inv = 1.f / (wsum + 1e-16f);
    const float* bf = b2 + q * 8;
    float4* ov = (float4*)(out + (size_t)n * 64 + q * 8);
    ov[0] = make_float4(acc[0] * inv + bf[0], acc[1] * inv + bf[1],
                        acc[2] * inv + bf[2], acc[3] * inv + bf[3]);
    ov[1] = make_float4(acc[4] * inv + bf[4], acc[5] * inv + bf[5],
                        acc[6] * inv + bf[6], acc[7] * inv + bf[7]);
}

extern "C" void kernel_launch(void* const* d_in, const int* in_sizes, int n_in,
                              void* d_out, int out_size, void* d_ws, size_t ws_size,
                              hipStream_t stream) {
    (void)n_in; (void)out_size; (void)ws_size;
    const float* x   = (const float*)d_in[0];
    const int*   ei  = (const int*)d_in[1];
    const float* W1  = (const float*)d_in[2];
    const float* a1s = (const float*)d_in[3];
    const float* a1d = (const float*)d_in[4];
    const float* b1  = (const float*)d_in[5];
    const float* W2  = (const float*)d_in[6];
    const float* a2s = (const float*)d_in[7];
    const float* a2d = (const float*)d_in[8];
    const float* b2  = (const float*)d_in[9];
    float* out = (float*)d_out;

    const int N = in_sizes[0] / 128;
    const int E = in_sizes[1] / 2;
    const int* src = ei;
    const int* dst = ei + E;

    char* wp = (char*)d_ws;
    auto alloc = [&](size_t bytes) -> void* {
        void* p = (void*)wp;
        wp += (bytes + 255) & ~(size_t)255;
        return p;
    };
    __half* h1   = (__half*)alloc((size_t)N * 128 * 2);
    __half* act1 = (__half*)alloc((size_t)N * 128 * 2);
    __half* h2   = (__half*)alloc((size_t)N * 64 * 2 + 64 * 256);  // +pad for gemm2 tail
    float* al1s = (float*)alloc((size_t)N * 8 * 4);
    float* al1d = (float*)alloc((size_t)N * 8 * 4);
    float* al2s = (float*)alloc((size_t)N * 4);
    float* al2d = (float*)alloc((size_t)N * 4);
    int* deg8     = (int*)alloc((size_t)N * 8 * 4);    // 8 XCD-local copies
    int* bucketCnt = (int*)alloc(8 * 16 * 4);          // contiguous after deg8 (one memset)
    int* rowstart = (int*)alloc((size_t)(N + 1) * 4);
    int* cursor   = (int*)alloc((size_t)N * PAD * 4);  // 1 counter / 64B line
    int* esrc     = (int*)alloc((size_t)E * 4);
    int2* pairs   = (int2*)alloc((size_t)8 * E * 8);   // per-bucket lists, cap E each
    int* blocksum = (int*)alloc(256 * 4);
    _Float16* W1t = (_Float16*)alloc(144 * 128 * 2);
    _Float16* W2t = (_Float16*)alloc(80 * 128 * 2);

    const int nbScan = (N + 255) / 256;
    const int gridH  = (E + 1023) / 1024;
    const int gridG1 = (N + 63) / 64;
    const int gridG2 = (N + 63) / 64;
    const int bdiv = (N + 7) / 8;
    const int gridAggN = 8 * ((bdiv + 31) / 32);
    // phase-B: enough chunks to cover expected bucket size in one round;
    // grid-stride handles any imbalance.
    const int nChunk = ((E + 7) / 8 + 1023) / 1024 + 2;
    const int gridScat = 8 * nChunk;

    // zero deg8 + bucketCnt in one memset (bucketCnt allocated contiguously)
    hipMemsetAsync(deg8, 0, (size_t)N * 8 * 4 + 8 * 16 * 4, stream);

    // K1: augw ∥ (hist + bucket phase A)
    augw_hist_kernel<<<2 + gridH, 256, 0, stream>>>(W1, a1s, a1d, W2, a2s, a2d,
                                                    W1t, W2t, src, dst, E, N,
                                                    deg8, bucketCnt, pairs);
    scan1_kernel<<<nbScan, 256, 0, stream>>>(deg8, N, rowstart, blocksum);
    scan23_kernel<<<(N + 256) / 256, 256, 0, stream>>>(rowstart, blocksum, nbScan,
                                                       cursor, N, E);
    // K4: gemm1 ∥ scatter phase B
    gemm1_scatter_kernel<<<gridG1 + gridScat, 256, 0, stream>>>(
        x, W1t, h1, al1s, al1d, N, gridG1, bucketCnt, pairs, E, nChunk,
        cursor, esrc);

    agg1_kernel<<<gridAggN, 256, 0, stream>>>(h1, al1s, al1d, rowstart, esrc, b1, act1, N);
    gemm2_kernel<<<gridG2, 256, 0, stream>>>(act1, W2t, h2, al2s, al2d, N);
    agg2_kernel<<<gridAggN, 256, 0, stream>>>(h2, al2s, al2d, rowstart, esrc, b2, out, N);
}